// Round 3
// baseline (76.839 us; speedup 1.0000x reference)
//
#include <hip/hip_runtime.h>

#define BB 128
#define MM 256
#define NN (BB * MM)          // 32768 atoms
#define PP 2097152            // fixed pair-list length
#define RCF 5.0f
#define NBLK 512              // 128 structures x 4 row-blocks
#define GTH (NBLK * 256)

typedef unsigned long long u64;

// ---------------------------------------------------------------------------
// ws layout: flags u64[NBLK] | tot u64[1] | partials float[3*128]
// ---------------------------------------------------------------------------

// K1: per-block (256-atom) coord minima -> partials[128][3]; also zero the
// lookback flags + total slot (fresh every call; graph-safe, deterministic).
__global__ void __launch_bounds__(256)
min_k(const float* __restrict__ coord, float* __restrict__ partials,
      u64* __restrict__ flags) {
    const int g = blockIdx.x * 256 + threadIdx.x;
    if (g < NBLK + 1) flags[g] = 0ULL;   // flags[0..511] + tot slot
    float x = coord[3 * g + 0];
    float y = coord[3 * g + 1];
    float z = coord[3 * g + 2];
    #pragma unroll
    for (int off = 32; off > 0; off >>= 1) {
        x = fminf(x, __shfl_xor(x, off, 64));
        y = fminf(y, __shfl_xor(y, off, 64));
        z = fminf(z, __shfl_xor(z, off, 64));
    }
    __shared__ float lx[4], ly[4], lz[4];
    const int w = threadIdx.x >> 6;
    if ((threadIdx.x & 63) == 0) { lx[w] = x; ly[w] = y; lz[w] = z; }
    __syncthreads();
    if (threadIdx.x == 0) {
        partials[3 * blockIdx.x + 0] = fminf(fminf(lx[0], lx[1]), fminf(lx[2], lx[3]));
        partials[3 * blockIdx.x + 1] = fminf(fminf(ly[0], ly[1]), fminf(ly[2], ly[3]));
        partials[3 * blockIdx.x + 2] = fminf(fminf(lz[0], lz[1]), fminf(lz[2], lz[3]));
    }
}

__device__ inline void reduce_min128(const float* __restrict__ partials,
                                     float& mnx, float& mny, float& mnz) {
    const int lane = threadIdx.x & 63;
    float x = fminf(partials[3 * lane + 0], partials[3 * (lane + 64) + 0]);
    float y = fminf(partials[3 * lane + 1], partials[3 * (lane + 64) + 1]);
    float z = fminf(partials[3 * lane + 2], partials[3 * (lane + 64) + 2]);
    #pragma unroll
    for (int off = 32; off > 0; off >>= 1) {
        x = fminf(x, __shfl_xor(x, off, 64));
        y = fminf(y, __shfl_xor(y, off, 64));
        z = fminf(z, __shfl_xor(z, off, 64));
    }
    mnx = x; mny = y; mnz = z;
}

__device__ inline void zero_range(float* __restrict__ o, int lo, int hi, int g) {
    // hi is always a multiple of 4 here
    int a = (lo + 3) & ~3;
    if (a > hi) a = hi;
    if (g < a - lo) o[lo + g] = 0.0f;
    float4* o4 = reinterpret_cast<float4*>(o);
    const float4 z4 = make_float4(0.f, 0.f, 0.f, 0.f);
    for (int q = (a >> 2) + g; q < (hi >> 2); q += GTH) o4[q] = z4;
}

// ---------------------------------------------------------------------------
// K2 (fused): count (bitmask) -> block scan -> decoupled-lookback global scan
// -> emit pairs -> tail zero. Block b2 = b*4+rblk owns rows rblk*64..+64 of
// structure b; thread t = i_loc*4 + c handles (row i_loc, j-chunk c); global
// slot b2*256+t is lexicographic in (b,i,j). fp32 arithmetic replicates the
// reference exactly: pos=coord-min (rn sub), diff=pos_j-pos_i,
// sq=((dx*dx+dy*dy)+dz*dz) no-FMA, dist=rn sqrt, mask=(sq>0)&(dist<5).
// flags[i]: (flag<<32)|value; flag 0=invalid, 1=aggregate, 2=inclusive prefix.
// ---------------------------------------------------------------------------
__global__ void __launch_bounds__(256)
pairs_k(const float* __restrict__ coord, const float* __restrict__ partials,
        u64* __restrict__ flags, u64* __restrict__ tot,
        float* __restrict__ outF) {
    const int b2 = blockIdx.x;
    const int b = b2 >> 2, rblk = b2 & 3;
    const int t = threadIdx.x;
    const int lane = t & 63, w = t >> 6;

    float mnx, mny, mnz;
    reduce_min128(partials, mnx, mny, mnz);

    __shared__ float sx[256], sy[256], sz[256];
    __shared__ int wsum[4];
    __shared__ int sBase, sTot;

    const int ja = b * MM + t;
    sx[t] = __fsub_rn(coord[3 * ja + 0], mnx);
    sy[t] = __fsub_rn(coord[3 * ja + 1], mny);
    sz[t] = __fsub_rn(coord[3 * ja + 2], mnz);
    __syncthreads();

    const int i_loc = t >> 2, c = t & 3;
    const int row = rblk * 64 + i_loc;
    const float pix = sx[row], piy = sy[row], piz = sz[row];
    const int j0 = c * 64;

    // pass 1: count + hit bitmask
    unsigned m0 = 0u, m1 = 0u;
    int cnt = 0;
    for (int jj = 0; jj < 64; ++jj) {
        float dx = __fsub_rn(sx[j0 + jj], pix);
        float dy = __fsub_rn(sy[j0 + jj], piy);
        float dz = __fsub_rn(sz[j0 + jj], piz);
        float sq = __fadd_rn(__fadd_rn(__fmul_rn(dx, dx), __fmul_rn(dy, dy)),
                             __fmul_rn(dz, dz));
        if (sq > 0.0f && __fsqrt_rn(sq) < RCF) {
            cnt++;
            if (jj < 32) m0 |= (1u << jj); else m1 |= (1u << (jj - 32));
        }
    }

    // wave-level inclusive scan of cnt, then cross-wave offsets via LDS
    int incl = cnt;
    #pragma unroll
    for (int off = 1; off < 64; off <<= 1) {
        int v = __shfl_up(incl, off, 64);
        if (lane >= off) incl += v;
    }
    if (lane == 63) wsum[w] = incl;
    __syncthreads();
    const int agg = wsum[0] + wsum[1] + wsum[2] + wsum[3];
    int woff = 0;
    for (int k = 0; k < w; ++k) woff += wsum[k];
    const int lexcl = woff + incl - cnt;     // block-local exclusive prefix

    // publish aggregate so successors can progress
    if (t == 0)
        __hip_atomic_store(&flags[b2], (1ULL << 32) | (unsigned)agg,
                           __ATOMIC_RELEASE, __HIP_MEMORY_SCOPE_AGENT);

    // wave-parallel decoupled lookback (wave 0 only)
    if (w == 0) {
        long long acc = 0;
        int look = b2 - 1;
        while (look >= 0) {
            const int idx = look - lane;
            u64 s = (idx >= 0)
                ? __hip_atomic_load(&flags[idx], __ATOMIC_ACQUIRE,
                                    __HIP_MEMORY_SCOPE_AGENT)
                : (2ULL << 32);                    // virtual block -1: prefix 0
            const unsigned f = (unsigned)(s >> 32);
            const int v = (int)(unsigned)s;
            const u64 bal0 = __ballot(f == 0u);
            const u64 bal2 = __ballot(f == 2u);
            const int k2 = bal2 ? (__ffsll(bal2) - 1) : 64;
            const u64 below = (k2 >= 64) ? ~0ULL : ((1ULL << k2) - 1ULL);
            if ((bal0 & below) == 0ULL) {
                int contrib = (k2 >= 64) ? v : ((lane <= (unsigned)k2) ? v : 0);
                #pragma unroll
                for (int off = 32; off > 0; off >>= 1)
                    contrib += __shfl_xor(contrib, off, 64);
                acc += contrib;
                if (k2 < 64) break;                // hit an inclusive prefix
                look -= 64;                        // whole window was aggregates
            }
            // else: some needed flag still 0 -> retry window
        }
        if (lane == 0) sBase = (int)acc;
    }
    __syncthreads();
    const int base = sBase;

    // publish inclusive prefix; last block publishes grand total
    if (t == 0) {
        __hip_atomic_store(&flags[b2], (2ULL << 32) | (unsigned)(base + agg),
                           __ATOMIC_RELEASE, __HIP_MEMORY_SCOPE_AGENT);
        if (b2 == NBLK - 1)
            __hip_atomic_store(tot, (1ULL << 32) | (unsigned)(base + agg),
                               __ATOMIC_RELEASE, __HIP_MEMORY_SCOPE_AGENT);
    }

    // pass 2: emit only the hit bits (recompute exact values)
    int p = base + lexcl;
    const int gi = b * MM + row;
    const int gj0 = b * MM + j0;
    #pragma unroll
    for (int half = 0; half < 2; ++half) {
        unsigned mm = half ? m1 : m0;
        const int jbase = half * 32;
        while (mm) {
            const int bit = __ffs(mm) - 1;
            mm &= mm - 1;
            const int jj = jbase + bit;
            float dx = __fsub_rn(sx[j0 + jj], pix);
            float dy = __fsub_rn(sy[j0 + jj], piy);
            float dz = __fsub_rn(sz[j0 + jj], piz);
            float sq = __fadd_rn(__fadd_rn(__fmul_rn(dx, dx), __fmul_rn(dy, dy)),
                                 __fmul_rn(dz, dz));
            float dist = __fsqrt_rn(sq);
            if (p < PP) {
                outF[2 * p + 0] = (float)gi;
                outF[2 * p + 1] = (float)(gj0 + jj);
                outF[2 * PP + p] = dist;
                const int dfb = 3 * PP + 3 * p;
                outF[dfb + 0] = dx;
                outF[dfb + 1] = dy;
                outF[dfb + 2] = dz;
            }
            p++;
        }
    }

    // wait for grand total, then zero the tail (disjoint from pair region)
    if (t == 0) {
        u64 s;
        do {
            s = __hip_atomic_load(tot, __ATOMIC_ACQUIRE, __HIP_MEMORY_SCOPE_AGENT);
        } while ((s >> 32) == 0ULL);
        sTot = (int)(unsigned)s;
    }
    __syncthreads();
    const int total = sTot;

    const int g = b2 * 256 + t;
    zero_range(outF, 2 * total,              2 * PP, g);
    zero_range(outF, 2 * PP + total,         3 * PP, g);
    zero_range(outF, 3 * PP + 3 * total,     6 * PP, g);
}

extern "C" void kernel_launch(void* const* d_in, const int* in_sizes, int n_in,
                              void* d_out, int out_size, void* d_ws, size_t ws_size,
                              hipStream_t stream) {
    const float* coord = (const float*)d_in[0];
    // d_in[1] (ind_1) structurally encoded (B contiguous blocks of M); unused.
    float* outF = (float*)d_out;

    u64*   flags    = (u64*)d_ws;                          // [NBLK] + tot at [NBLK]
    u64*   tot      = flags + NBLK;
    float* partials = (float*)(flags + NBLK + 1);          // 384 floats

    min_k  <<<128,  256, 0, stream>>>(coord, partials, flags);
    pairs_k<<<NBLK, 256, 0, stream>>>(coord, partials, flags, tot, outF);
}

// Round 7
// 32.355 us; speedup vs baseline: 2.3748x; 2.3748x over previous
//
#include <hip/hip_runtime.h>

#define BB 128
#define MM 256
#define NN (BB * MM)          // 32768 atoms
#define PP 2097152            // fixed pair-list length
#define RCF 5.0f
#define NBLK 512              // 128 structures x 4 row-blocks
#define GTH (NBLK * 256)
#define CAP 2048              // staged pairs per flush batch

typedef unsigned long long u64;

// ws layout: masks u64[GTH] | bsums int[NBLK] | partials float[3*128]

// ---------------------------------------------------------------------------
// K1: per-block (256-atom) coord minima -> partials[128][3]. Unconditional
// writes; no init/atomics. fmin is exact & order-independent, so any
// reduction order matches jnp.min bitwise.
// ---------------------------------------------------------------------------
__global__ void __launch_bounds__(256)
min_k(const float* __restrict__ coord, float* __restrict__ partials) {
    const int g = blockIdx.x * 256 + threadIdx.x;
    float x = coord[3 * g + 0];
    float y = coord[3 * g + 1];
    float z = coord[3 * g + 2];
    #pragma unroll
    for (int off = 32; off > 0; off >>= 1) {
        x = fminf(x, __shfl_xor(x, off, 64));
        y = fminf(y, __shfl_xor(y, off, 64));
        z = fminf(z, __shfl_xor(z, off, 64));
    }
    __shared__ float lx[4], ly[4], lz[4];
    const int w = threadIdx.x >> 6;
    if ((threadIdx.x & 63) == 0) { lx[w] = x; ly[w] = y; lz[w] = z; }
    __syncthreads();
    if (threadIdx.x == 0) {
        partials[3 * blockIdx.x + 0] = fminf(fminf(lx[0], lx[1]), fminf(lx[2], lx[3]));
        partials[3 * blockIdx.x + 1] = fminf(fminf(ly[0], ly[1]), fminf(ly[2], ly[3]));
        partials[3 * blockIdx.x + 2] = fminf(fminf(lz[0], lz[1]), fminf(lz[2], lz[3]));
    }
}

__device__ inline void reduce_min128(const float* __restrict__ partials,
                                     float& mnx, float& mny, float& mnz) {
    const int lane = threadIdx.x & 63;
    float x = fminf(partials[3 * lane + 0], partials[3 * (lane + 64) + 0]);
    float y = fminf(partials[3 * lane + 1], partials[3 * (lane + 64) + 1]);
    float z = fminf(partials[3 * lane + 2], partials[3 * (lane + 64) + 2]);
    #pragma unroll
    for (int off = 32; off > 0; off >>= 1) {
        x = fminf(x, __shfl_xor(x, off, 64));
        y = fminf(y, __shfl_xor(y, off, 64));
        z = fminf(z, __shfl_xor(z, off, 64));
    }
    mnx = x; mny = y; mnz = z;
}

// ---------------------------------------------------------------------------
// Geometry: block b2 = b*4 + rblk owns rows rblk*64..+64 of structure b;
// thread t = i_loc*4 + c handles (row i_loc, j-chunk c); global slot
// b2*256+t is lexicographic in (b,i,j). Tiles padded [4][65] so the 4 chunk
// base addresses (c*65+jj) land in distinct LDS banks.
// fp32 replicates reference exactly: pos=coord-min (rn sub), diff=pos_j-pos_i,
// sq=((dx*dx+dy*dy)+dz*dz) no-FMA, dist=rn sqrt, mask=(sq>0)&(dist<5).
// ---------------------------------------------------------------------------

// K2: hit bitmask per thread + per-block pair totals.
__global__ void __launch_bounds__(256)
count_k(const float* __restrict__ coord, const float* __restrict__ partials,
        u64* __restrict__ masks, int* __restrict__ bsums) {
    const int b2 = blockIdx.x;
    const int b = b2 >> 2, rblk = b2 & 3;
    const int t = threadIdx.x;
    const int lane = t & 63, w = t >> 6;
    float mnx, mny, mnz;
    reduce_min128(partials, mnx, mny, mnz);

    __shared__ float sx[4][65], sy[4][65], sz[4][65];
    __shared__ int wsum[4];
    const int ja = b * MM + t;
    sx[t >> 6][t & 63] = __fsub_rn(coord[3 * ja + 0], mnx);
    sy[t >> 6][t & 63] = __fsub_rn(coord[3 * ja + 1], mny);
    sz[t >> 6][t & 63] = __fsub_rn(coord[3 * ja + 2], mnz);
    __syncthreads();

    const int i_loc = t >> 2, c = t & 3;
    const float pix = sx[rblk][i_loc], piy = sy[rblk][i_loc], piz = sz[rblk][i_loc];
    u64 m = 0ULL;
    for (int jj = 0; jj < 64; ++jj) {
        float dx = __fsub_rn(sx[c][jj], pix);
        float dy = __fsub_rn(sy[c][jj], piy);
        float dz = __fsub_rn(sz[c][jj], piz);
        float sq = __fadd_rn(__fadd_rn(__fmul_rn(dx, dx), __fmul_rn(dy, dy)),
                             __fmul_rn(dz, dz));
        if (sq > 0.0f && __fsqrt_rn(sq) < RCF) m |= (1ULL << jj);
    }
    masks[b2 * 256 + t] = m;

    int v = __popcll(m);
    #pragma unroll
    for (int off = 32; off > 0; off >>= 1) v += __shfl_xor(v, off, 64);
    if (lane == 0) wsum[w] = v;
    __syncthreads();
    if (t == 0) bsums[b2] = wsum[0] + wsum[1] + wsum[2] + wsum[3];
}

__device__ inline void zero_range(float* __restrict__ o, int lo, int hi, int g) {
    // hi is always a multiple of 4 here
    int a = (lo + 3) & ~3;
    if (a > hi) a = hi;
    if (g < a - lo) o[lo + g] = 0.0f;
    float4* o4 = reinterpret_cast<float4*>(o);
    const float4 z4 = make_float4(0.f, 0.f, 0.f, 0.f);
    for (int q = (a >> 2) + g; q < (hi >> 2); q += GTH) o4[q] = z4;
}

// K3: redundant scan of bsums -> base/total; emit pairs via LDS-staged,
// fully-coalesced flushes; float4 tail-zero. Output (floats): ind2 [0,2P)
// as {gi,gj}, d [2P,3P), df [3P,6P). Pair region + tail partition the
// buffer: every element written exactly once.
__global__ void __launch_bounds__(256)
write_k(const float* __restrict__ coord, const float* __restrict__ partials,
        const u64* __restrict__ masks, const int* __restrict__ bsums,
        float* __restrict__ outF) {
    const int b2 = blockIdx.x;
    const int b = b2 >> 2, rblk = b2 & 3;
    const int t = threadIdx.x;
    const int lane = t & 63, w = t >> 6;
    float mnx, mny, mnz;
    reduce_min128(partials, mnx, mny, mnz);

    __shared__ float sx[4][65], sy[4][65], sz[4][65];
    __shared__ int tmp[256];
    __shared__ int pre[NBLK];
    __shared__ int sTotS;
    __shared__ int wsum[4];
    __shared__ float sd[CAP];        // dist plane
    __shared__ float sind[2 * CAP];  // {gi,gj} plane (as float)
    __shared__ float sdf[3 * CAP];   // {dx,dy,dz} plane

    const int ja = b * MM + t;
    sx[t >> 6][t & 63] = __fsub_rn(coord[3 * ja + 0], mnx);
    sy[t >> 6][t & 63] = __fsub_rn(coord[3 * ja + 1], mny);
    sz[t >> 6][t & 63] = __fsub_rn(coord[3 * ja + 2], mnz);

    // redundant exclusive scan of 512 block sums (2 per thread)
    const int v0 = bsums[2 * t], v1 = bsums[2 * t + 1];
    const int s01 = v0 + v1;
    tmp[t] = s01;
    __syncthreads();
    #pragma unroll
    for (int off = 1; off < 256; off <<= 1) {
        int v = (t >= off) ? tmp[t - off] : 0;
        __syncthreads();
        tmp[t] += v;
        __syncthreads();
    }
    const int excl = tmp[t] - s01;
    pre[2 * t] = excl;
    pre[2 * t + 1] = excl + v0;
    if (t == 255) sTotS = excl + s01;
    __syncthreads();

    const int base = pre[b2];
    const int total = (sTotS < PP) ? sTotS : PP;

    // per-thread mask -> count -> block-local exclusive offset + block total
    const u64 mask = masks[b2 * 256 + t];
    const int cnt = __popcll(mask);
    int incl = cnt;
    #pragma unroll
    for (int off = 1; off < 64; off <<= 1) {
        int v = __shfl_up(incl, off, 64);
        if (lane >= off) incl += v;
    }
    if (lane == 63) wsum[w] = incl;
    __syncthreads();
    const int agg = wsum[0] + wsum[1] + wsum[2] + wsum[3];
    int woff = 0;
    for (int k = 0; k < w; ++k) woff += wsum[k];
    const int lexcl = woff + incl - cnt;

    const int i_loc = t >> 2, c = t & 3;
    const float pix = sx[rblk][i_loc], piy = sy[rblk][i_loc], piz = sz[rblk][i_loc];
    const int gi = b * MM + rblk * 64 + i_loc;
    const int gj0 = b * MM + c * 64;

    // batched staged emission (uniform batch count; agg is block-uniform)
    const int nbat = (agg + CAP - 1) / CAP;
    for (int bb = 0; bb < nbat; ++bb) {
        const int wlo = bb * CAP, whi = wlo + CAP;
        int q = lexcl;
        u64 mm = mask;
        while (mm) {
            const int jj = __ffsll((long long)mm) - 1;
            mm &= mm - 1;
            if (q >= whi) break;
            if (q >= wlo) {
                float dx = __fsub_rn(sx[c][jj], pix);
                float dy = __fsub_rn(sy[c][jj], piy);
                float dz = __fsub_rn(sz[c][jj], piz);
                float sq = __fadd_rn(__fadd_rn(__fmul_rn(dx, dx), __fmul_rn(dy, dy)),
                                     __fmul_rn(dz, dz));
                const int s = q - wlo;
                sd[s] = __fsqrt_rn(sq);
                sind[2 * s + 0] = (float)gi;
                sind[2 * s + 1] = (float)(gj0 + jj);
                sdf[3 * s + 0] = dx;
                sdf[3 * s + 1] = dy;
                sdf[3 * s + 2] = dz;
            }
            q++;
        }
        __syncthreads();
        const int nq = ((agg - wlo) < CAP) ? (agg - wlo) : CAP;
        const int pbase = base + wlo;               // global pair idx of slot 0
        int rem = PP - pbase; if (rem < 0) rem = 0;
        const int nv = (nq < rem) ? nq : rem;       // clamp at PP
        for (int k = t; k < nv; k += 256)     outF[2 * PP + pbase + k]     = sd[k];
        for (int k = t; k < 2 * nv; k += 256) outF[2 * pbase + k]          = sind[k];
        for (int k = t; k < 3 * nv; k += 256) outF[3 * PP + 3 * pbase + k] = sdf[k];
        __syncthreads();
    }

    // tail zeroing (disjoint from pair region; coalesced float4)
    const int g = b2 * 256 + t;
    zero_range(outF, 2 * total,          2 * PP, g);
    zero_range(outF, 2 * PP + total,     3 * PP, g);
    zero_range(outF, 3 * PP + 3 * total, 6 * PP, g);
}

extern "C" void kernel_launch(void* const* d_in, const int* in_sizes, int n_in,
                              void* d_out, int out_size, void* d_ws, size_t ws_size,
                              hipStream_t stream) {
    const float* coord = (const float*)d_in[0];
    // d_in[1] (ind_1) structurally encoded (B contiguous blocks of M); unused.
    float* outF = (float*)d_out;

    u64*   masks    = (u64*)d_ws;                          // GTH u64 = 1 MB
    int*   bsums    = (int*)(masks + GTH);                 // 512 ints
    float* partials = (float*)(bsums + NBLK);              // 384 floats

    min_k  <<<128,  256, 0, stream>>>(coord, partials);
    count_k<<<NBLK, 256, 0, stream>>>(coord, partials, masks, bsums);
    write_k<<<NBLK, 256, 0, stream>>>(coord, partials, masks, bsums, outF);
}